// Round 25
// baseline (103.727 us; speedup 1.0000x reference)
//
#include <hip/hip_runtime.h>
#include <hip/hip_cooperative_groups.h>
#include <cmath>

namespace cg = cooperative_groups;

#define S_   128
#define W_   64
#define D_   200
#define H_   50
#define OUT_ 5
#define JW   13   // scan: columns per wave (4*13 = 52 >= 50; tail guarded)

__device__ __forceinline__ float rcp_fast(float x) {
    return __builtin_amdgcn_rcpf(x);
}
__device__ __forceinline__ float tanh_fast(float x) {
    float e = __expf(2.f * x);
    return (e - 1.f) * rcp_fast(e + 1.f);
}
__device__ __forceinline__ float sigmoid_fast(float x) {
    return rcp_fast(1.f + __expf(-x));
}
__device__ __forceinline__ float bcast(float v, int lane) {
    return __int_as_float(__builtin_amdgcn_readlane(__float_as_int(v), lane));
}
// lgkmcnt-only barrier: ds-writes drained, vmcnt (X prefetch) stays in flight
__device__ __forceinline__ void barrier_lds_only() {
    asm volatile("s_waitcnt lgkmcnt(0)" ::: "memory");
    __builtin_amdgcn_s_barrier();
    __builtin_amdgcn_sched_barrier(0);
}

// ---------------------------------------------------------------------------
// Fused kernel (v13): phase 1 = per-sentence conv+pool-commuted projection
// (all 128 blocks, = the old k_sent); grid.sync(); phase 2 = the v12 GRNN
// scan (block 0 only, 4-wave column-split, fast gates, padded exchange,
// lgkmcnt-only barrier -- measured 51.7us). Fusion removes the second
// launch + inter-kernel drain (~10-12us of the 16.5us non-scan time).
// ---------------------------------------------------------------------------
__global__ __launch_bounds__(256, 1) void k_fused(
    const int* __restrict__ doc, const float* __restrict__ emb,
    const float* __restrict__ w_word, const float* __restrict__ b_word,
    const float* __restrict__ cw1, const float* __restrict__ cb1,
    const float* __restrict__ cw2, const float* __restrict__ cb2,
    const float* __restrict__ cw3, const float* __restrict__ cb3,
    const float* __restrict__ Wi, const float* __restrict__ bi,
    const float* __restrict__ Wf, const float* __restrict__ bf,
    const float* __restrict__ Wr, const float* __restrict__ br,
    const float* __restrict__ Ui, const float* __restrict__ Uf,
    const float* __restrict__ Ur,
    const float* __restrict__ Wout, const float* __restrict__ bout,
    float* __restrict__ X,         // ws: [3][S_][H_]
    float* __restrict__ out)
{
    const int tid = threadIdx.x;

    // ---- phase 1: sentence front end (every block, s = blockIdx.x) ----
    {
        const int s = blockIdx.x;

        __shared__ int   drow[W_];
        __shared__ float vec[5][D_];
        __shared__ float q[5][H_];
        __shared__ float m[6][H_ + 2];
        __shared__ float reps_sh[H_];

        if (tid < W_) drow[tid] = doc[s * W_ + tid];
        __syncthreads();

        if (tid < D_) {
            const int d = tid;
            float acc = 0.f;
            for (int u = 0; u < W_; ++u)
                acc += emb[(size_t)drow[u] * D_ + d];
            vec[0][d] = acc;
            vec[1][d] = emb[(size_t)drow[0]      * D_ + d];
            vec[2][d] = emb[(size_t)drow[1]      * D_ + d];
            vec[3][d] = emb[(size_t)drow[W_ - 2] * D_ + d];
            vec[4][d] = emb[(size_t)drow[W_ - 1] * D_ + d];
        }
        __syncthreads();

        if (tid < 5 * H_) {
            const int v = tid / H_, h = tid % H_;
            const float* wr = w_word + h * D_;
            float acc = 0.f;
            for (int d = 0; d < D_; ++d) acc += wr[d] * vec[v][d];
            q[v][h] = acc;
        }
        __syncthreads();

        if (tid < H_) {
            const int h = tid;
            const float qf = q[0][h], q0 = q[1][h], q1 = q[2][h],
                        q62 = q[3][h], q63 = q[4][h];
            const float bw = b_word[h];
            m[0][h] = qf               * (1.f / 64.f) + bw;
            m[1][h] = (qf - q63)       * (1.f / 63.f) + bw;
            m[2][h] = (qf - q0)        * (1.f / 63.f) + bw;
            m[3][h] = (qf - q62 - q63) * (1.f / 62.f) + bw;
            m[4][h] = (qf - q0  - q63) * (1.f / 62.f) + bw;
            m[5][h] = (qf - q0  - q1)  * (1.f / 62.f) + bw;
        }
        __syncthreads();

        if (tid < H_) {
            const int o = tid;
            float a1 = cb1[o], a2 = cb2[o], a3 = cb3[o];
            for (int i = 0; i < H_; ++i) {
                a1 += cw1[o * H_ + i] * m[0][i];
                const float* c2 = cw2 + (o * H_ + i) * 2;
                a2 += c2[0] * m[1][i] + c2[1] * m[2][i];
                const float* c3 = cw3 + (o * H_ + i) * 3;
                a3 += c3[0] * m[3][i] + c3[1] * m[4][i] + c3[2] * m[5][i];
            }
            reps_sh[o] = (tanhf(a1) + tanhf(a2) + tanhf(a3)) * (1.f / 3.f);
        }
        __syncthreads();

        if (tid < 3 * H_) {
            const int g = tid / H_, o = tid % H_;
            const float* Wg = (g == 0) ? Wi : (g == 1) ? Wf : Wr;
            const float* bg = (g == 0) ? bi : (g == 1) ? bf : br;
            float acc = bg[o];
            for (int j = 0; j < H_; ++j) acc += Wg[o * H_ + j] * reps_sh[j];
            X[(g * S_ + s) * H_ + o] = acc;
        }
        __threadfence();               // publish X device-wide before sync
    }

    cg::this_grid().sync();

    // ---- phase 2: GRNN scan (block 0 only; v12 structure verbatim) ----
    if (blockIdx.x != 0) return;
    {
        const int w   = tid >> 6;                 // wave: 0..3
        const int o   = tid & 63;
        const int ro  = (o < H_) ? o : (H_ - 1);
        const int jlo = w * JW;

        __shared__ float part[2][3][64][5];       // padded: 0 bank conflicts

        float ua[JW], ub[JW], uc[JW];
        {
            const float* Uir = Ui + ro * H_;
            const float* Ufr = Uf + ro * H_;
            const float* Urr = Ur + ro * H_;
            #pragma unroll
            for (int jj = 0; jj < JW; ++jj) {
                const int j = jlo + jj;
                const bool ok = (j < H_);
                ua[jj] = ok ? Uir[j] : 0.f;
                ub[jj] = ok ? Ufr[j] : 0.f;
                uc[jj] = ok ? Urr[j] : 0.f;
            }
        }

        float h  = 0.f;
        float xi = X[(0 * S_ + 0) * H_ + ro];
        float xf = X[(1 * S_ + 0) * H_ + ro];
        float xr = X[(2 * S_ + 0) * H_ + ro];

        int p = 0;
        for (int t = 0; t < S_; ++t) {
            const int tn = (t + 1 < S_) ? (t + 1) : (S_ - 1);
            float nxi = X[(0 * S_ + tn) * H_ + ro];
            float nxf = X[(1 * S_ + tn) * H_ + ro];
            float nxr = X[(2 * S_ + tn) * H_ + ro];

            float hj[JW];
            #pragma unroll
            for (int jj = 0; jj < JW; ++jj) {
                const int j  = jlo + jj;
                const int jl = (j < H_) ? j : (H_ - 1);
                hj[jj] = bcast(h, jl);
            }

            float pi0 = 0.f, pi1 = 0.f, pf0 = 0.f, pf1 = 0.f,
                  pr0 = 0.f, pr1 = 0.f;
            #pragma unroll
            for (int jj = 0; jj + 1 < JW; jj += 2) {
                pi0 += ua[jj]     * hj[jj];
                pf0 += ub[jj]     * hj[jj];
                pr0 += uc[jj]     * hj[jj];
                pi1 += ua[jj + 1] * hj[jj + 1];
                pf1 += ub[jj + 1] * hj[jj + 1];
                pr1 += uc[jj + 1] * hj[jj + 1];
            }
            pi0 += ua[JW - 1] * hj[JW - 1];
            pf0 += ub[JW - 1] * hj[JW - 1];
            pr0 += uc[JW - 1] * hj[JW - 1];

            part[p][0][o][w] = pi0 + pi1;
            part[p][1][o][w] = pf0 + pf1;
            part[p][2][o][w] = pr0 + pr1;
            barrier_lds_only();

            float ai = xi + (part[p][0][o][0] + part[p][0][o][1])
                          + (part[p][0][o][2] + part[p][0][o][3]);
            float af = xf + (part[p][1][o][0] + part[p][1][o][1])
                          + (part[p][1][o][2] + part[p][1][o][3]);
            float ar = xr + (part[p][2][o][0] + part[p][2][o][1])
                          + (part[p][2][o][2] + part[p][2][o][3]);

            float gi = sigmoid_fast(ai);
            float gf = sigmoid_fast(af);
            float gg = tanh_fast(ar);
            h = tanh_fast(gi * gg + gf * h);

            xi = nxi; xf = nxf; xr = nxr;
            p ^= 1;
        }

        float logit = (o < OUT_) ? bout[o] : 0.f;
        const float* wrow = Wout + ((o < OUT_) ? o : 0) * H_;
        #pragma unroll
        for (int j = 0; j < H_; ++j) {
            float hj = bcast(h, j);
            logit += wrow[j] * hj;
        }
        float l0 = bcast(logit, 0), l1 = bcast(logit, 1),
              l2 = bcast(logit, 2), l3 = bcast(logit, 3),
              l4 = bcast(logit, 4);
        float mx = fmaxf(fmaxf(fmaxf(l0, l1), fmaxf(l2, l3)), l4);
        float e0 = __expf(l0 - mx), e1 = __expf(l1 - mx),
              e2 = __expf(l2 - mx), e3 = __expf(l3 - mx),
              e4 = __expf(l4 - mx);
        float s = e0 + e1 + e2 + e3 + e4;
        if (tid == 0) {
            float rs = 1.f / s;
            out[0] = e0 * rs; out[1] = e1 * rs; out[2] = e2 * rs;
            out[3] = e3 * rs; out[4] = e4 * rs;
        }
    }
}

extern "C" void kernel_launch(void* const* d_in, const int* in_sizes, int n_in,
                              void* d_out, int out_size, void* d_ws, size_t ws_size,
                              hipStream_t stream) {
    (void)in_sizes; (void)n_in; (void)out_size; (void)ws_size;

    const int*   doc    = (const int*)  d_in[0];
    const float* emb    = (const float*)d_in[1];
    const float* w_word = (const float*)d_in[2];
    const float* b_word = (const float*)d_in[3];
    const float* cw1    = (const float*)d_in[4];
    const float* cb1    = (const float*)d_in[5];
    const float* cw2    = (const float*)d_in[6];
    const float* cb2    = (const float*)d_in[7];
    const float* cw3    = (const float*)d_in[8];
    const float* cb3    = (const float*)d_in[9];
    const float* Wi     = (const float*)d_in[10];
    const float* Ui     = (const float*)d_in[11];
    const float* bi     = (const float*)d_in[12];
    const float* Wf     = (const float*)d_in[13];
    const float* Uf     = (const float*)d_in[14];
    const float* bf     = (const float*)d_in[15];
    const float* Wr     = (const float*)d_in[16];
    const float* Ur     = (const float*)d_in[17];
    const float* br     = (const float*)d_in[18];
    const float* Wout   = (const float*)d_in[19];
    const float* bout   = (const float*)d_in[20];

    float* X   = (float*)d_ws;               // [3][S_][H_] f32 = 76.8 KB
    float* out = (float*)d_out;

    void* args[] = {
        (void*)&doc, (void*)&emb, (void*)&w_word, (void*)&b_word,
        (void*)&cw1, (void*)&cb1, (void*)&cw2, (void*)&cb2,
        (void*)&cw3, (void*)&cb3, (void*)&Wi, (void*)&bi,
        (void*)&Wf, (void*)&bf, (void*)&Wr, (void*)&br,
        (void*)&Ui, (void*)&Uf, (void*)&Ur,
        (void*)&Wout, (void*)&bout, (void*)&X, (void*)&out
    };
    hipLaunchCooperativeKernel((const void*)k_fused, dim3(S_), dim3(256),
                               args, 0, stream);
}

// Round 26
// 75.897 us; speedup vs baseline: 1.3667x; 1.3667x over previous
//
#include <hip/hip_runtime.h>
#include <cmath>

#define S_   128
#define W_   64
#define D_   200
#define H_   50
#define OUT_ 5
#define JW   13   // scan: columns per wave (4*13 = 52 >= 50; tail guarded)

__device__ __forceinline__ float rcp_fast(float x) {
    return __builtin_amdgcn_rcpf(x);
}
__device__ __forceinline__ float tanh_fast(float x) {
    float e = __expf(2.f * x);
    return (e - 1.f) * rcp_fast(e + 1.f);
}
__device__ __forceinline__ float sigmoid_fast(float x) {
    return rcp_fast(1.f + __expf(-x));
}
__device__ __forceinline__ float bcast(float v, int lane) {
    return __int_as_float(__builtin_amdgcn_readlane(__float_as_int(v), lane));
}
// lgkmcnt-only barrier: ds-writes drained, vmcnt (X prefetch) stays in flight
__device__ __forceinline__ void barrier_lds_only() {
    asm volatile("s_waitcnt lgkmcnt(0)" ::: "memory");
    __builtin_amdgcn_s_barrier();
    __builtin_amdgcn_sched_barrier(0);
}

// ---------------------------------------------------------------------------
// Fused kernel (v14): 129 blocks. Blocks 0..127 = sentence front end (the
// proven k_sent); each signals a device-scope counter when its X rows are
// published. Block 128 = the v12 scan; it spin-waits (s_sleep) until all 128
// signals, then runs. v13's cg::this_grid().sync() cost ~35us (fused 88-94us
// vs 51.7+6 of work) -- the cooperative barrier, not fusion, was the
// regression. 129 blocks x 4 waves co-resident by capacity (<=256 CUs), so
// the spin is deadlock-free; atomics are device-scope (cross-XCD safe).
// Counter is reset by hipMemsetAsync each call -> deterministic replays.
// ---------------------------------------------------------------------------
__global__ __launch_bounds__(256) void k_fused(
    const int* __restrict__ doc, const float* __restrict__ emb,
    const float* __restrict__ w_word, const float* __restrict__ b_word,
    const float* __restrict__ cw1, const float* __restrict__ cb1,
    const float* __restrict__ cw2, const float* __restrict__ cb2,
    const float* __restrict__ cw3, const float* __restrict__ cb3,
    const float* __restrict__ Wi, const float* __restrict__ bi,
    const float* __restrict__ Wf, const float* __restrict__ bf,
    const float* __restrict__ Wr, const float* __restrict__ br,
    const float* __restrict__ Ui, const float* __restrict__ Uf,
    const float* __restrict__ Ur,
    const float* __restrict__ Wout, const float* __restrict__ bout,
    float* __restrict__ X,             // ws: [3][S_][H_]
    unsigned int* __restrict__ done,   // ws: counter (memset to 0 per call)
    float* __restrict__ out)
{
    const int tid = threadIdx.x;

    if (blockIdx.x < S_) {
        // ---- phase 1: sentence front end (blocks 0..127) ----
        const int s = blockIdx.x;

        __shared__ int   drow[W_];
        __shared__ float vec[5][D_];
        __shared__ float q[5][H_];
        __shared__ float m[6][H_ + 2];
        __shared__ float reps_sh[H_];

        if (tid < W_) drow[tid] = doc[s * W_ + tid];
        __syncthreads();

        if (tid < D_) {
            const int d = tid;
            float acc = 0.f;
            for (int u = 0; u < W_; ++u)
                acc += emb[(size_t)drow[u] * D_ + d];
            vec[0][d] = acc;
            vec[1][d] = emb[(size_t)drow[0]      * D_ + d];
            vec[2][d] = emb[(size_t)drow[1]      * D_ + d];
            vec[3][d] = emb[(size_t)drow[W_ - 2] * D_ + d];
            vec[4][d] = emb[(size_t)drow[W_ - 1] * D_ + d];
        }
        __syncthreads();

        if (tid < 5 * H_) {
            const int v = tid / H_, h = tid % H_;
            const float* wr = w_word + h * D_;
            float acc = 0.f;
            for (int d = 0; d < D_; ++d) acc += wr[d] * vec[v][d];
            q[v][h] = acc;
        }
        __syncthreads();

        if (tid < H_) {
            const int h = tid;
            const float qf = q[0][h], q0 = q[1][h], q1 = q[2][h],
                        q62 = q[3][h], q63 = q[4][h];
            const float bw = b_word[h];
            m[0][h] = qf               * (1.f / 64.f) + bw;
            m[1][h] = (qf - q63)       * (1.f / 63.f) + bw;
            m[2][h] = (qf - q0)        * (1.f / 63.f) + bw;
            m[3][h] = (qf - q62 - q63) * (1.f / 62.f) + bw;
            m[4][h] = (qf - q0  - q63) * (1.f / 62.f) + bw;
            m[5][h] = (qf - q0  - q1)  * (1.f / 62.f) + bw;
        }
        __syncthreads();

        if (tid < H_) {
            const int o = tid;
            float a1 = cb1[o], a2 = cb2[o], a3 = cb3[o];
            for (int i = 0; i < H_; ++i) {
                a1 += cw1[o * H_ + i] * m[0][i];
                const float* c2 = cw2 + (o * H_ + i) * 2;
                a2 += c2[0] * m[1][i] + c2[1] * m[2][i];
                const float* c3 = cw3 + (o * H_ + i) * 3;
                a3 += c3[0] * m[3][i] + c3[1] * m[4][i] + c3[2] * m[5][i];
            }
            reps_sh[o] = (tanhf(a1) + tanhf(a2) + tanhf(a3)) * (1.f / 3.f);
        }
        __syncthreads();

        if (tid < 3 * H_) {
            const int g = tid / H_, o = tid % H_;
            const float* Wg = (g == 0) ? Wi : (g == 1) ? Wf : Wr;
            const float* bg = (g == 0) ? bi : (g == 1) ? bf : br;
            float acc = bg[o];
            for (int j = 0; j < H_; ++j) acc += Wg[o * H_ + j] * reps_sh[j];
            X[(g * S_ + s) * H_ + o] = acc;
        }
        __syncthreads();
        if (tid == 0) {
            __threadfence();                 // release: X visible device-wide
            atomicAdd(done, 1u);             // device-scope signal
        }
        return;
    }

    // ---- phase 2: GRNN scan (block 128; v12 structure verbatim) ----
    {
        // wait for all 128 producers (spin on tid 0, cheap s_sleep loop)
        if (tid == 0) {
            while (atomicAdd(done, 0u) < (unsigned)S_) {
                __builtin_amdgcn_s_sleep(8);
            }
            __threadfence();                 // acquire
        }
        __syncthreads();

        const int w   = tid >> 6;                 // wave: 0..3
        const int o   = tid & 63;
        const int ro  = (o < H_) ? o : (H_ - 1);
        const int jlo = w * JW;

        __shared__ float part[2][3][64][5];       // padded: 0 bank conflicts

        float ua[JW], ub[JW], uc[JW];
        {
            const float* Uir = Ui + ro * H_;
            const float* Ufr = Uf + ro * H_;
            const float* Urr = Ur + ro * H_;
            #pragma unroll
            for (int jj = 0; jj < JW; ++jj) {
                const int j = jlo + jj;
                const bool ok = (j < H_);
                ua[jj] = ok ? Uir[j] : 0.f;
                ub[jj] = ok ? Ufr[j] : 0.f;
                uc[jj] = ok ? Urr[j] : 0.f;
            }
        }

        float h  = 0.f;
        float xi = X[(0 * S_ + 0) * H_ + ro];
        float xf = X[(1 * S_ + 0) * H_ + ro];
        float xr = X[(2 * S_ + 0) * H_ + ro];

        int p = 0;
        for (int t = 0; t < S_; ++t) {
            const int tn = (t + 1 < S_) ? (t + 1) : (S_ - 1);
            float nxi = X[(0 * S_ + tn) * H_ + ro];
            float nxf = X[(1 * S_ + tn) * H_ + ro];
            float nxr = X[(2 * S_ + tn) * H_ + ro];

            float hj[JW];
            #pragma unroll
            for (int jj = 0; jj < JW; ++jj) {
                const int j  = jlo + jj;
                const int jl = (j < H_) ? j : (H_ - 1);
                hj[jj] = bcast(h, jl);
            }

            float pi0 = 0.f, pi1 = 0.f, pf0 = 0.f, pf1 = 0.f,
                  pr0 = 0.f, pr1 = 0.f;
            #pragma unroll
            for (int jj = 0; jj + 1 < JW; jj += 2) {
                pi0 += ua[jj]     * hj[jj];
                pf0 += ub[jj]     * hj[jj];
                pr0 += uc[jj]     * hj[jj];
                pi1 += ua[jj + 1] * hj[jj + 1];
                pf1 += ub[jj + 1] * hj[jj + 1];
                pr1 += uc[jj + 1] * hj[jj + 1];
            }
            pi0 += ua[JW - 1] * hj[JW - 1];
            pf0 += ub[JW - 1] * hj[JW - 1];
            pr0 += uc[JW - 1] * hj[JW - 1];

            part[p][0][o][w] = pi0 + pi1;
            part[p][1][o][w] = pf0 + pf1;
            part[p][2][o][w] = pr0 + pr1;
            barrier_lds_only();

            float ai = xi + (part[p][0][o][0] + part[p][0][o][1])
                          + (part[p][0][o][2] + part[p][0][o][3]);
            float af = xf + (part[p][1][o][0] + part[p][1][o][1])
                          + (part[p][1][o][2] + part[p][1][o][3]);
            float ar = xr + (part[p][2][o][0] + part[p][2][o][1])
                          + (part[p][2][o][2] + part[p][2][o][3]);

            float gi = sigmoid_fast(ai);
            float gf = sigmoid_fast(af);
            float gg = tanh_fast(ar);
            h = tanh_fast(gi * gg + gf * h);

            xi = nxi; xf = nxf; xr = nxr;
            p ^= 1;
        }

        float logit = (o < OUT_) ? bout[o] : 0.f;
        const float* wrow = Wout + ((o < OUT_) ? o : 0) * H_;
        #pragma unroll
        for (int j = 0; j < H_; ++j) {
            float hj = bcast(h, j);
            logit += wrow[j] * hj;
        }
        float l0 = bcast(logit, 0), l1 = bcast(logit, 1),
              l2 = bcast(logit, 2), l3 = bcast(logit, 3),
              l4 = bcast(logit, 4);
        float mx = fmaxf(fmaxf(fmaxf(l0, l1), fmaxf(l2, l3)), l4);
        float e0 = __expf(l0 - mx), e1 = __expf(l1 - mx),
              e2 = __expf(l2 - mx), e3 = __expf(l3 - mx),
              e4 = __expf(l4 - mx);
        float s = e0 + e1 + e2 + e3 + e4;
        if (tid == 0) {
            float rs = 1.f / s;
            out[0] = e0 * rs; out[1] = e1 * rs; out[2] = e2 * rs;
            out[3] = e3 * rs; out[4] = e4 * rs;
        }
    }
}

extern "C" void kernel_launch(void* const* d_in, const int* in_sizes, int n_in,
                              void* d_out, int out_size, void* d_ws, size_t ws_size,
                              hipStream_t stream) {
    (void)in_sizes; (void)n_in; (void)out_size; (void)ws_size;

    const int*   doc    = (const int*)  d_in[0];
    const float* emb    = (const float*)d_in[1];
    const float* w_word = (const float*)d_in[2];
    const float* b_word = (const float*)d_in[3];
    const float* cw1    = (const float*)d_in[4];
    const float* cb1    = (const float*)d_in[5];
    const float* cw2    = (const float*)d_in[6];
    const float* cb2    = (const float*)d_in[7];
    const float* cw3    = (const float*)d_in[8];
    const float* cb3    = (const float*)d_in[9];
    const float* Wi     = (const float*)d_in[10];
    const float* Ui     = (const float*)d_in[11];
    const float* bi     = (const float*)d_in[12];
    const float* Wf     = (const float*)d_in[13];
    const float* Uf     = (const float*)d_in[14];
    const float* bf     = (const float*)d_in[15];
    const float* Wr     = (const float*)d_in[16];
    const float* Ur     = (const float*)d_in[17];
    const float* br     = (const float*)d_in[18];
    const float* Wout   = (const float*)d_in[19];
    const float* bout   = (const float*)d_in[20];

    float*        X    = (float*)d_ws;                       // 76.8 KB
    unsigned int* done = (unsigned int*)((char*)d_ws + 80 * 1024);
    float*        out  = (float*)d_out;

    hipMemsetAsync(done, 0, sizeof(unsigned int), stream);   // deterministic
    k_fused<<<S_ + 1, 256, 0, stream>>>(doc, emb, w_word, b_word,
                                        cw1, cb1, cw2, cb2, cw3, cb3,
                                        Wi, bi, Wf, bf, Wr, br,
                                        Ui, Uf, Ur, Wout, bout,
                                        X, done, out);
}

// Round 28
// 68.217 us; speedup vs baseline: 1.5205x; 1.1126x over previous
//
#include <hip/hip_runtime.h>
#include <cmath>

#define S_   128
#define W_   64
#define D_   200
#define H_   50
#define OUT_ 5

// ---------------------------------------------------------------------------
// Kernel 1: one block per sentence (conv+pool commuted into the projection).
// ---------------------------------------------------------------------------
__global__ __launch_bounds__(256) void k_sent(
    const int* __restrict__ doc, const float* __restrict__ emb,
    const float* __restrict__ w_word, const float* __restrict__ b_word,
    const float* __restrict__ cw1, const float* __restrict__ cb1,
    const float* __restrict__ cw2, const float* __restrict__ cb2,
    const float* __restrict__ cw3, const float* __restrict__ cb3,
    const float* __restrict__ Wi, const float* __restrict__ bi,
    const float* __restrict__ Wf, const float* __restrict__ bf,
    const float* __restrict__ Wr, const float* __restrict__ br,
    float* __restrict__ Xout)   // [3][S_][H_]
{
    const int s   = blockIdx.x;
    const int tid = threadIdx.x;

    __shared__ int   drow[W_];
    __shared__ float vec[5][D_];     // full sum, E0, E1, E62, E63
    __shared__ float q[5][H_];       // w_word @ each of the above
    __shared__ float m[6][H_ + 2];   // the 6 window means
    __shared__ float reps_sh[H_];

    if (tid < W_) drow[tid] = doc[s * W_ + tid];
    __syncthreads();

    if (tid < D_) {
        const int d = tid;
        float acc = 0.f;
        for (int u = 0; u < W_; ++u)
            acc += emb[(size_t)drow[u] * D_ + d];
        vec[0][d] = acc;
        vec[1][d] = emb[(size_t)drow[0]      * D_ + d];
        vec[2][d] = emb[(size_t)drow[1]      * D_ + d];
        vec[3][d] = emb[(size_t)drow[W_ - 2] * D_ + d];
        vec[4][d] = emb[(size_t)drow[W_ - 1] * D_ + d];
    }
    __syncthreads();

    if (tid < 5 * H_) {
        const int v = tid / H_, h = tid % H_;
        const float* wr = w_word + h * D_;
        float acc = 0.f;
        for (int d = 0; d < D_; ++d) acc += wr[d] * vec[v][d];
        q[v][h] = acc;
    }
    __syncthreads();

    if (tid < H_) {
        const int h = tid;
        const float qf = q[0][h], q0 = q[1][h], q1 = q[2][h],
                    q62 = q[3][h], q63 = q[4][h];
        const float bw = b_word[h];
        m[0][h] = qf               * (1.f / 64.f) + bw;
        m[1][h] = (qf - q63)       * (1.f / 63.f) + bw;
        m[2][h] = (qf - q0)        * (1.f / 63.f) + bw;
        m[3][h] = (qf - q62 - q63) * (1.f / 62.f) + bw;
        m[4][h] = (qf - q0  - q63) * (1.f / 62.f) + bw;
        m[5][h] = (qf - q0  - q1)  * (1.f / 62.f) + bw;
    }
    __syncthreads();

    if (tid < H_) {
        const int o = tid;
        float a1 = cb1[o], a2 = cb2[o], a3 = cb3[o];
        for (int i = 0; i < H_; ++i) {
            a1 += cw1[o * H_ + i] * m[0][i];
            const float* c2 = cw2 + (o * H_ + i) * 2;
            a2 += c2[0] * m[1][i] + c2[1] * m[2][i];
            const float* c3 = cw3 + (o * H_ + i) * 3;
            a3 += c3[0] * m[3][i] + c3[1] * m[4][i] + c3[2] * m[5][i];
        }
        reps_sh[o] = (tanhf(a1) + tanhf(a2) + tanhf(a3)) * (1.f / 3.f);
    }
    __syncthreads();

    if (tid < 3 * H_) {
        const int g = tid / H_, o = tid % H_;
        const float* Wg = (g == 0) ? Wi : (g == 1) ? Wf : Wr;
        const float* bg = (g == 0) ? bi : (g == 1) ? bf : br;
        float acc = bg[o];
        for (int j = 0; j < H_; ++j) acc += Wg[o * H_ + j] * reps_sh[j];
        Xout[(g * S_ + s) * H_ + o] = acc;
    }
}

// ---------------------------------------------------------------------------
// Kernel 2 (v12 champion, restored): 4-wave column-split scan + fast gates +
// [64][5]-padded exchange (0 bank conflicts) + lgkmcnt-only barrier + batched
// broadcasts/dual accumulators. Measured 51.7us. Both fusion variants (cg
// grid.sync v13: 88-94us; spin-barrier v14: 81-84us) regressed ~25-35us from
// in-kernel sync + cross-XCD dirty-L2 X reads -- the two-kernel form gets a
// free writeback at k_sent's end, so scan X reads are clean, prefetch-hidden.
// Structural floor: 128 serial steps x (LDS exchange round-trip + gate
// chain) ~= 970 cyc/step; no associative-scan decomposition for GRNN gates.
// ---------------------------------------------------------------------------
#define JW 13   // columns per wave (4*13 = 52 >= 50; tail guarded)

__device__ __forceinline__ float rcp_fast(float x) {
    return __builtin_amdgcn_rcpf(x);
}

__device__ __forceinline__ float tanh_fast(float x) {
    float e = __expf(2.f * x);
    return (e - 1.f) * rcp_fast(e + 1.f);
}

__device__ __forceinline__ float sigmoid_fast(float x) {
    return rcp_fast(1.f + __expf(-x));
}

__device__ __forceinline__ float bcast(float v, int lane) {
    return __int_as_float(__builtin_amdgcn_readlane(__float_as_int(v), lane));
}

// lgkmcnt-only barrier: ds-writes drained, vmcnt (X prefetch) stays in flight
__device__ __forceinline__ void barrier_lds_only() {
    asm volatile("s_waitcnt lgkmcnt(0)" ::: "memory");
    __builtin_amdgcn_s_barrier();
    __builtin_amdgcn_sched_barrier(0);
}

__global__ __launch_bounds__(256, 1) void k_scan(
    const float* __restrict__ X,   // [3][S_][H_]
    const float* __restrict__ Ui, const float* __restrict__ Uf,
    const float* __restrict__ Ur,
    const float* __restrict__ Wout, const float* __restrict__ bout,
    float* __restrict__ out)
{
    const int tid = threadIdx.x;
    const int w   = tid >> 6;                 // wave: 0..3
    const int o   = tid & 63;
    const int ro  = (o < H_) ? o : (H_ - 1);  // clamped row, all lanes in-bounds
    const int jlo = w * JW;                   // this wave's column window

    // part[parity][gate][o][wave(+pad)]: stride 5 -> conflict-free (v8: 0)
    __shared__ float part[2][3][64][5];

    float ua[JW], ub[JW], uc[JW];
    {
        const float* Uir = Ui + ro * H_;
        const float* Ufr = Uf + ro * H_;
        const float* Urr = Ur + ro * H_;
        #pragma unroll
        for (int jj = 0; jj < JW; ++jj) {
            const int j = jlo + jj;
            const bool ok = (j < H_);
            ua[jj] = ok ? Uir[j] : 0.f;
            ub[jj] = ok ? Ufr[j] : 0.f;
            uc[jj] = ok ? Urr[j] : 0.f;
        }
    }

    float h  = 0.f;                            // lane o holds h[o] (all waves)
    float xi = X[(0 * S_ + 0) * H_ + ro];
    float xf = X[(1 * S_ + 0) * H_ + ro];
    float xr = X[(2 * S_ + 0) * H_ + ro];

    int p = 0;
    for (int t = 0; t < S_; ++t) {
        const int tn = (t + 1 < S_) ? (t + 1) : (S_ - 1);   // clamped prefetch
        float nxi = X[(0 * S_ + tn) * H_ + ro];
        float nxf = X[(1 * S_ + tn) * H_ + ro];
        float nxr = X[(2 * S_ + tn) * H_ + ro];

        // batch all broadcasts first (independent; only depend on h)
        float hj[JW];
        #pragma unroll
        for (int jj = 0; jj < JW; ++jj) {
            const int j  = jlo + jj;
            const int jl = (j < H_) ? j : (H_ - 1);  // wave-uniform SGPR index
            hj[jj] = bcast(h, jl);
        }

        // six concurrent FMA chains: 2 accumulators per gate, depth 7
        float pi0 = 0.f, pi1 = 0.f, pf0 = 0.f, pf1 = 0.f,
              pr0 = 0.f, pr1 = 0.f;
        #pragma unroll
        for (int jj = 0; jj + 1 < JW; jj += 2) {
            pi0 += ua[jj]     * hj[jj];
            pf0 += ub[jj]     * hj[jj];
            pr0 += uc[jj]     * hj[jj];
            pi1 += ua[jj + 1] * hj[jj + 1];
            pf1 += ub[jj + 1] * hj[jj + 1];
            pr1 += uc[jj + 1] * hj[jj + 1];
        }
        pi0 += ua[JW - 1] * hj[JW - 1];        // JW odd: tail on chain 0
        pf0 += ub[JW - 1] * hj[JW - 1];
        pr0 += uc[JW - 1] * hj[JW - 1];

        part[p][0][o][w] = pi0 + pi1;
        part[p][1][o][w] = pf0 + pf1;
        part[p][2][o][w] = pr0 + pr1;
        barrier_lds_only();                    // ds_writes drained; X in flight

        float ai = xi + (part[p][0][o][0] + part[p][0][o][1])
                      + (part[p][0][o][2] + part[p][0][o][3]);
        float af = xf + (part[p][1][o][0] + part[p][1][o][1])
                      + (part[p][1][o][2] + part[p][1][o][3]);
        float ar = xr + (part[p][2][o][0] + part[p][2][o][1])
                      + (part[p][2][o][2] + part[p][2][o][3]);

        float gi = sigmoid_fast(ai);
        float gf = sigmoid_fast(af);
        float gg = tanh_fast(ar);
        h = tanh_fast(gi * gg + gf * h);       // identical in all waves

        xi = nxi; xf = nxf; xr = nxr;
        p ^= 1;                                // double buffer: no 2nd barrier
    }

    // output head (all waves compute identically; tid 0 stores)
    float logit = (o < OUT_) ? bout[o] : 0.f;
    const float* wrow = Wout + ((o < OUT_) ? o : 0) * H_;
    #pragma unroll
    for (int j = 0; j < H_; ++j) {
        float hj = bcast(h, j);
        logit += wrow[j] * hj;
    }
    float l0 = bcast(logit, 0), l1 = bcast(logit, 1), l2 = bcast(logit, 2),
          l3 = bcast(logit, 3), l4 = bcast(logit, 4);
    float mx = fmaxf(fmaxf(fmaxf(l0, l1), fmaxf(l2, l3)), l4);
    float e0 = __expf(l0 - mx), e1 = __expf(l1 - mx), e2 = __expf(l2 - mx),
          e3 = __expf(l3 - mx), e4 = __expf(l4 - mx);
    float s = e0 + e1 + e2 + e3 + e4;
    if (tid == 0) {
        float rs = 1.f / s;   // one IEEE div in the epilogue is fine
        out[0] = e0 * rs; out[1] = e1 * rs; out[2] = e2 * rs;
        out[3] = e3 * rs; out[4] = e4 * rs;
    }
}

extern "C" void kernel_launch(void* const* d_in, const int* in_sizes, int n_in,
                              void* d_out, int out_size, void* d_ws, size_t ws_size,
                              hipStream_t stream) {
    (void)in_sizes; (void)n_in; (void)out_size; (void)ws_size;

    const int*   doc    = (const int*)  d_in[0];
    const float* emb    = (const float*)d_in[1];
    const float* w_word = (const float*)d_in[2];
    const float* b_word = (const float*)d_in[3];
    const float* cw1    = (const float*)d_in[4];
    const float* cb1    = (const float*)d_in[5];
    const float* cw2    = (const float*)d_in[6];
    const float* cb2    = (const float*)d_in[7];
    const float* cw3    = (const float*)d_in[8];
    const float* cb3    = (const float*)d_in[9];
    const float* Wi     = (const float*)d_in[10];
    const float* Ui     = (const float*)d_in[11];
    const float* bi     = (const float*)d_in[12];
    const float* Wf     = (const float*)d_in[13];
    const float* Uf     = (const float*)d_in[14];
    const float* bf     = (const float*)d_in[15];
    const float* Wr     = (const float*)d_in[16];
    const float* Ur     = (const float*)d_in[17];
    const float* br     = (const float*)d_in[18];
    const float* Wout   = (const float*)d_in[19];
    const float* bout   = (const float*)d_in[20];

    float* X = (float*)d_ws;                 // [3][S_][H_] f32 = 76.8 KB
    float* out = (float*)d_out;

    k_sent<<<S_, 256, 0, stream>>>(doc, emb, w_word, b_word,
                                   cw1, cb1, cw2, cb2, cw3, cb3,
                                   Wi, bi, Wf, bf, Wr, br, X);
    k_scan<<<1, 256, 0, stream>>>(X, Ui, Uf, Ur, Wout, bout, out);
}